// Round 7
// baseline (280.552 us; speedup 1.0000x reference)
//
#include <hip/hip_runtime.h>
#include <hip/hip_bf16.h>

// B=4, S=2048, TEXT_DIM=768, VISION_DIM=768, HIDDEN=512, HEADS=8, HEAD_DIM=64
#define BATCH 4
#define SEQ 2048
#define TDIM 768
#define VDIM 768
#define HID 512
#define NHEADS 8
#define HDIM 64
#define MROWS (BATCH * SEQ)   // 8192
#define NQKV (3 * HID)        // 1536

typedef unsigned short ushort_t;
typedef __attribute__((ext_vector_type(8))) short short8;
typedef __attribute__((ext_vector_type(4))) short short4v;
typedef __attribute__((ext_vector_type(4))) float floatx4;

// 0.125 * log2(e): folded into Q so softmax uses exp2
#define QSCALE 0.18033688011112042f

__device__ __forceinline__ ushort_t bf16_rne(float f) {
    unsigned int u = __float_as_uint(f);
    u = (u + 0x7fffu + ((u >> 16) & 1u)) >> 16;
    return (ushort_t)u;
}

__device__ __forceinline__ void async16(const ushort_t* g, ushort_t* l) {
    __builtin_amdgcn_global_load_lds(
        (const __attribute__((address_space(1))) unsigned int*)g,
        (__attribute__((address_space(3))) unsigned int*)l, 16, 0, 0);
}

// ---------------------------------------------------------------------------
// Pre-pass A: X fp32 -> bf16 (8192x768)
// ---------------------------------------------------------------------------
__global__ __launch_bounds__(256) void conv_x(const float* __restrict__ X,
                                              ushort_t* __restrict__ Xb)
{
    const int i = (blockIdx.x * 256 + threadIdx.x) * 4;
    const floatx4 v = *(const floatx4*)(X + i);
    short4v o;
#pragma unroll
    for (int j = 0; j < 4; ++j) o[j] = (short)bf16_rne(v[j]);
    *(short4v*)(Xb + i) = o;
}

// ---------------------------------------------------------------------------
// Pre-pass B: weight transposes -> bf16 [N][K].
// ---------------------------------------------------------------------------
__global__ __launch_bounds__(256) void transp_w(
    const float* __restrict__ Wq, const float* __restrict__ Wk,
    const float* __restrict__ Wv, const float* __restrict__ Wo,
    ushort_t* __restrict__ Wqkvt, ushort_t* __restrict__ Wot)
{
    __shared__ float tile[32][33];
    const int z = blockIdx.z;
    const float* src;
    ushort_t* dst;
    int R, C;
    if (z < 3) {
        src = (z == 0) ? Wq : (z == 1) ? Wk : Wv;
        dst = Wqkvt + (size_t)z * HID * TDIM;
        R = TDIM; C = HID;
    } else {
        src = Wo; dst = Wot; R = HID; C = VDIM;
    }
    const int tx = threadIdx.x & 31, ty = threadIdx.x >> 5;  // 32 x 8
    const int c0 = blockIdx.x * 32, r0 = blockIdx.y * 32;
    if (c0 >= C || r0 >= R) return;
#pragma unroll
    for (int i = 0; i < 4; ++i)
        tile[ty + i * 8][tx] = src[(size_t)(r0 + ty + i * 8) * C + c0 + tx];
    __syncthreads();
#pragma unroll
    for (int i = 0; i < 4; ++i)
        dst[(size_t)(c0 + ty + i * 8) * R + r0 + tx] = bf16_rne(tile[tx][ty + i * 8]);
}

// ---------------------------------------------------------------------------
// m97-style bf16 MFMA GEMM mainloop: C(128x128) = A[M][K] x Bt[N][K]^T.
// (v3-verbatim: __syncthreads() drains global_load_lds, verified passing.)
// ---------------------------------------------------------------------------
template<int KD, bool SWAPPED>
__device__ __forceinline__ void gemm128(
    const ushort_t* __restrict__ A, const ushort_t* __restrict__ Bt,
    int m0, int n0, ushort_t* As, ushort_t* Bs, floatx4 (&acc)[4][4])
{
    const int tid  = threadIdx.x;
    const int lane = tid & 63;
    const int w    = tid >> 6;
    const int l15  = lane & 15;
    const int quad = lane >> 4;
    const int wrow = w >> 1;
    const int wcol = w & 1;

    const int srow = lane >> 3;        // 0..7
    const int scol = (lane & 7) * 8;   // k elem offset

    const ushort_t* ga = A  + (size_t)(m0 + w * 32 + srow) * KD + scol;
    const ushort_t* gb = Bt + (size_t)(n0 + w * 32 + srow) * KD + scol;
    ushort_t* la = As + (w * 32) * 64;
    ushort_t* lb = Bs + (w * 32) * 64;

    for (int kt = 0; kt < KD; kt += 64) {
#pragma unroll
        for (int i = 0; i < 4; ++i) {
            async16(ga + (size_t)(i * 8) * KD + kt, la + i * 8 * 64);
            async16(gb + (size_t)(i * 8) * KD + kt, lb + i * 8 * 64);
        }
        __syncthreads();
#pragma unroll
        for (int half = 0; half < 2; ++half) {
            const int kk = half * 32 + quad * 8;
            short8 af[4], bf[4];
#pragma unroll
            for (int t = 0; t < 4; ++t) {
                af[t] = *(const short8*)&As[(wrow * 64 + t * 16 + l15) * 64 + kk];
                bf[t] = *(const short8*)&Bs[(wcol * 64 + t * 16 + l15) * 64 + kk];
            }
#pragma unroll
            for (int mi = 0; mi < 4; ++mi)
#pragma unroll
                for (int ni = 0; ni < 4; ++ni) {
                    if (SWAPPED)
                        acc[mi][ni] = __builtin_amdgcn_mfma_f32_16x16x32_bf16(
                            bf[ni], af[mi], acc[mi][ni], 0, 0, 0);
                    else
                        acc[mi][ni] = __builtin_amdgcn_mfma_f32_16x16x32_bf16(
                            af[mi], bf[ni], acc[mi][ni], 0, 0, 0);
                }
        }
        __syncthreads();
    }
}

// ---------------------------------------------------------------------------
// Kernel 1: QKV projection, bf16 MFMA.
// ---------------------------------------------------------------------------
__global__ __launch_bounds__(256) void qkv_gemm_mfma(
    const ushort_t* __restrict__ Xb, const ushort_t* __restrict__ Wt,
    const float* __restrict__ bq, const float* __restrict__ bk,
    const float* __restrict__ bv,
    ushort_t* __restrict__ Q, ushort_t* __restrict__ K, ushort_t* __restrict__ V)
{
    __shared__ __align__(16) ushort_t As[128 * 64];
    __shared__ __align__(16) ushort_t Bs[128 * 64];

    const int bx = blockIdx.x;          // 0..11
    const int m0 = blockIdx.y * 128;
    const int n0 = bx * 128;
    const int which = bx >> 2;          // 0=Q 1=K 2=V
    const bool isV = (which == 2);

    floatx4 acc[4][4];
#pragma unroll
    for (int i = 0; i < 4; ++i)
#pragma unroll
        for (int j = 0; j < 4; ++j) acc[i][j] = (floatx4)0.0f;

    if (isV) gemm128<TDIM, false>(Xb, Wt, m0, n0, As, Bs, acc);
    else     gemm128<TDIM, true >(Xb, Wt, m0, n0, As, Bs, acc);

    const int lane = threadIdx.x & 63;
    const int w    = threadIdx.x >> 6;
    const int l15  = lane & 15;
    const int quad = lane >> 4;
    const int wrow = w >> 1;
    const int wcol = w & 1;

    if (!isV) {
        const float* bias = (which == 0) ? bq : bk;
        const float scale = (which == 0) ? QSCALE : 1.0f;
        ushort_t* Out = (which == 0) ? Q : K;
#pragma unroll
        for (int mi = 0; mi < 4; ++mi) {
            const int m = m0 + wrow * 64 + mi * 16 + l15;
            const int b = m >> 11;
            const int s = m & 2047;
#pragma unroll
            for (int ni = 0; ni < 4; ++ni) {
                const int c = (n0 - which * HID) + wcol * 64 + ni * 16 + quad * 4;
                const int h = c >> 6;
                const int d0 = c & 63;
                const floatx4 b4 = *(const floatx4*)(bias + c);
                short4v pk;
#pragma unroll
                for (int r = 0; r < 4; ++r)
                    pk[r] = (short)bf16_rne((acc[mi][ni][r] + b4[r]) * scale);
                *(short4v*)&Out[((size_t)(b * NHEADS + h) * SEQ + s) * HDIM + d0] = pk;
            }
        }
    } else {
#pragma unroll
        for (int ni = 0; ni < 4; ++ni) {
            const int c = (n0 - 2 * HID) + wcol * 64 + ni * 16 + l15;
            const int h = c >> 6;
            const int d = c & 63;
            const float b1 = bv[c];
#pragma unroll
            for (int mi = 0; mi < 4; ++mi) {
                const int mb = m0 + wrow * 64 + mi * 16 + quad * 4;
                const int b = mb >> 11;
                const int s0 = mb & 2047;
                short4v pk;
#pragma unroll
                for (int r = 0; r < 4; ++r)
                    pk[r] = (short)bf16_rne(acc[mi][ni][r] + b1);
                *(short4v*)&V[((size_t)(b * NHEADS + h) * HDIM + d) * SEQ + s0] = pk;
            }
        }
    }
}

// ---------------------------------------------------------------------------
// Kernel 2: MFMA flash attention v7 (bf16 in, bf16 out).
// = v3 (passed twice) with ONE change: K fragments are loaded DIRECTLY from
// global memory (VMEM/L1 pipe) instead of being staged into LDS.
// Rationale: round-1 counters showed the LDS read pipe as the wall (~41 of
// 47.7 us, K-reads + V-reads each ~20.5). Dual-qi halving failed twice
// (deterministic ~7.2e-3 miscompute, abandoned). Splitting the two streams
// across pipes runs them concurrently: V on LDS (v3-verbatim staging +
// swizzled ds_read_b128), K on VMEM with L1 reuse (8 waves/block re-read the
// same 8 KB K-tile -> L1-resident, L2 traffic ~1x like staging).
// kf addressing = the de-swizzled address v3's LDS reads resolved to:
//   kf0 = K[kt + t*16 + l15][quad*8 .. +7], kf1 = same + 32.  Math is
// bit-identical to v3. Ks buffer gone: LDS 32768 -> 16384 B -> 3-4 blocks/CU.
// ---------------------------------------------------------------------------
__global__ __launch_bounds__(512) void flash_attn_mfma(
    const ushort_t* __restrict__ Q, const ushort_t* __restrict__ K,
    const ushort_t* __restrict__ Vt, ushort_t* __restrict__ Att)
{
    __shared__ __align__(16) ushort_t Vs[2][64 * 64];   // [buf][d][kk]  (swizzled)

    const int tid  = threadIdx.x;
    const int lane = tid & 63;
    const int w    = tid >> 6;     // wave 0..7
    const int l15  = lane & 15;
    const int quad = lane >> 4;

    const int bh = blockIdx.y;
    const int b  = bh >> 3;
    const int h  = bh & 7;
    const int q0 = blockIdx.x * 128;

    const ushort_t* Qb = Q  + (size_t)bh * SEQ * HDIM;
    const ushort_t* Kb = K  + (size_t)bh * SEQ * HDIM;
    const ushort_t* Vb = Vt + (size_t)bh * HDIM * SEQ;

    // Q fragments (registers, whole kernel). B-operand: n=q=l15, k=d=quad*8+j
    short8 qf0, qf1;
    {
        const ushort_t* qrow = Qb + (size_t)(q0 + w * 16 + l15) * HDIM + quad * 8;
        qf0 = *(const short8*)(qrow);
        qf1 = *(const short8*)(qrow + 32);
    }

    floatx4 of[4];
#pragma unroll
    for (int t = 0; t < 4; ++t) of[t] = (floatx4)0.0f;
    floatx4 ofl = (floatx4)0.0f;          // l accumulator via ones-MFMA

    short8 ones;
#pragma unroll
    for (int j = 0; j < 8; ++j) ones[j] = (short)0x3F80;   // bf16 1.0

    const floatx4 z4 = (floatx4)0.0f;

    // V staging (v3-verbatim): wave w stages rows w*8..w*8+7 of each V-tile.
    // global source col16 is pre-swizzled so the LINEAR global_load_lds dest
    // (base + lane*16) lands the XOR-swizzled layout.
    const int srow = lane >> 3;                    // 0..7 = row&7
    const int scol = ((lane & 7) ^ srow) * 8;      // swizzled col (elems)
    const ushort_t* gv = Vb + (size_t)(w * 8 + srow) * SEQ + scol;
    ushort_t* lv0 = &Vs[0][w * 8 * 64];            // wave-uniform LDS bases
    ushort_t* lv1 = &Vs[1][w * 8 * 64];

    // V fragment read offsets (swizzle-aware): global col16 c of row r sits
    // at LDS slot c ^ (r&7); r&7 == l15&7 for all t (t*16 = 0 mod 8).
    const int off0 = (quad ^ (l15 & 7)) * 8;       // elems, kv half 0
    const int off1 = off0 ^ 32;                    // (slot^4)*8, half 1

    // K direct-load base: rows (kv) t*16+l15, cols quad*8 / +32.
    const ushort_t* gkf = Kb + (size_t)l15 * HDIM + quad * 8;

    auto tile = [&](const ushort_t* Vt_, int ktbase) {
        // ---- S^T = K . Q^T  (K fragments direct from global, L1-hit) ----
        floatx4 sacc[4];
        __builtin_amdgcn_s_setprio(1);
#pragma unroll
        for (int t = 0; t < 4; ++t) {
            const ushort_t* krow = gkf + (size_t)(ktbase + t * 16) * HDIM;
            const short8 kf0 = *(const short8*)(krow);
            const short8 kf1 = *(const short8*)(krow + 32);
            floatx4 a = z4;
            a = __builtin_amdgcn_mfma_f32_16x16x32_bf16(kf0, qf0, a, 0, 0, 0);
            a = __builtin_amdgcn_mfma_f32_16x16x32_bf16(kf1, qf1, a, 0, 0, 0);
            sacc[t] = a;
        }
        __builtin_amdgcn_s_setprio(0);

        // ---- p = exp2(s) (raw v_exp_f32), pack pairs to bf16x2 ----
        // lane holds p for q=l15, kv = 16t + 4*quad + r
        unsigned w0[4], w1[4];
#pragma unroll
        for (int t = 0; t < 4; ++t) {
            const float p0 = __builtin_amdgcn_exp2f(sacc[t][0]);
            const float p1 = __builtin_amdgcn_exp2f(sacc[t][1]);
            const float p2 = __builtin_amdgcn_exp2f(sacc[t][2]);
            const float p3 = __builtin_amdgcn_exp2f(sacc[t][3]);
            asm("v_cvt_pk_bf16_f32 %0, %1, %2" : "=v"(w0[t]) : "v"(p0), "v"(p1));
            asm("v_cvt_pk_bf16_f32 %0, %1, %2" : "=v"(w1[t]) : "v"(p2), "v"(p3));
        }

        // ---- in-register P^T redistribution (v3-verbatim) ----
        unsigned a0 = w0[0], b0 = w0[1];
        asm("v_permlane32_swap_b32 %0, %1" : "+v"(a0), "+v"(b0));
        asm("v_permlane16_swap_b32 %0, %1" : "+v"(a0), "+v"(b0));
        unsigned a1 = w1[0], b1 = w1[1];
        asm("v_permlane32_swap_b32 %0, %1" : "+v"(a1), "+v"(b1));
        asm("v_permlane16_swap_b32 %0, %1" : "+v"(a1), "+v"(b1));
        unsigned a2 = w0[2], b2 = w0[3];
        asm("v_permlane32_swap_b32 %0, %1" : "+v"(a2), "+v"(b2));
        asm("v_permlane16_swap_b32 %0, %1" : "+v"(a2), "+v"(b2));
        unsigned a3 = w1[2], b3 = w1[3];
        asm("v_permlane32_swap_b32 %0, %1" : "+v"(a3), "+v"(b3));
        asm("v_permlane16_swap_b32 %0, %1" : "+v"(a3), "+v"(b3));

        union { unsigned u[4]; short8 s; } P0, P1;
        P0.u[0] = a0; P0.u[1] = a1; P0.u[2] = b0; P0.u[3] = b1;   // kv 0..31
        P1.u[0] = a2; P1.u[1] = a3; P1.u[2] = b2; P1.u[3] = b3;   // kv 32..63
        const short8 pf0 = P0.s;
        const short8 pf1 = P1.s;

        // ---- O^T += V^T . P^T ; l += 1 . P^T (MFMA pipe) ----
        __builtin_amdgcn_s_setprio(1);
        ofl = __builtin_amdgcn_mfma_f32_16x16x32_bf16(ones, pf0, ofl, 0, 0, 0);
        ofl = __builtin_amdgcn_mfma_f32_16x16x32_bf16(ones, pf1, ofl, 0, 0, 0);
#pragma unroll
        for (int t = 0; t < 4; ++t) {
            const short8 vf0 = *(const short8*)&Vt_[(t * 16 + l15) * 64 + off0];
            const short8 vf1 = *(const short8*)&Vt_[(t * 16 + l15) * 64 + off1];
            of[t] = __builtin_amdgcn_mfma_f32_16x16x32_bf16(vf0, pf0, of[t], 0, 0, 0);
            of[t] = __builtin_amdgcn_mfma_f32_16x16x32_bf16(vf1, pf1, of[t], 0, 0, 0);
        }
        __builtin_amdgcn_s_setprio(0);
    };

    // prologue: V tile 0 into buf0
    async16(gv, lv0);

    for (int kt = 0; kt < SEQ; kt += 128) {
        __syncthreads();                       // drains buf0 V loads
        async16(gv + (kt + 64), lv1);          // prefetch V buf1
        tile(Vs[0], kt);

        __syncthreads();                       // drains buf1 V loads
        if (kt + 128 < SEQ) async16(gv + (kt + 128), lv0);  // prefetch V buf0
        tile(Vs[1], kt + 64);
    }

    // ---- epilogue: each lane already holds full l for its q=l15 ----
    const float inv = 1.f / ofl[0];

    const int s = q0 + w * 16 + l15;
    ushort_t* arow = Att + ((size_t)(b * SEQ + s)) * HID + h * HDIM;
#pragma unroll
    for (int t = 0; t < 4; ++t) {
        short4v pk;
#pragma unroll
        for (int r = 0; r < 4; ++r) pk[r] = (short)bf16_rne(of[t][r] * inv);
        *(short4v*)&arow[t * 16 + quad * 4] = pk;
    }
}

// ---------------------------------------------------------------------------
// Kernel 3: output projection, bf16 MFMA.
// ---------------------------------------------------------------------------
__global__ __launch_bounds__(256) void out_gemm_mfma(
    const ushort_t* __restrict__ Attb, const ushort_t* __restrict__ Wot,
    const float* __restrict__ bo, float* __restrict__ Y)
{
    __shared__ __align__(16) ushort_t As[128 * 64];
    __shared__ __align__(16) ushort_t Bs[128 * 64];

    const int m0 = blockIdx.y * 128;
    const int n0 = blockIdx.x * 128;

    floatx4 acc[4][4];
#pragma unroll
    for (int i = 0; i < 4; ++i)
#pragma unroll
        for (int j = 0; j < 4; ++j) acc[i][j] = (floatx4)0.0f;

    gemm128<HID, true>(Attb, Wot, m0, n0, As, Bs, acc);

    const int lane = threadIdx.x & 63;
    const int w    = threadIdx.x >> 6;
    const int l15  = lane & 15;
    const int quad = lane >> 4;
    const int wrow = w >> 1;
    const int wcol = w & 1;

#pragma unroll
    for (int mi = 0; mi < 4; ++mi) {
        const int m = m0 + wrow * 64 + mi * 16 + l15;
#pragma unroll
        for (int ni = 0; ni < 4; ++ni) {
            const int nb = n0 + wcol * 64 + ni * 16 + quad * 4;
            const floatx4 b4 = *(const floatx4*)(bo + nb);
            floatx4 o;
#pragma unroll
            for (int r = 0; r < 4; ++r) o[r] = acc[mi][ni][r] + b4[r];
            *(floatx4*)&Y[(size_t)m * VDIM + nb] = o;
        }
    }
}

// ---------------------------------------------------------------------------
extern "C" void kernel_launch(void* const* d_in, const int* in_sizes, int n_in,
                              void* d_out, int out_size, void* d_ws, size_t ws_size,
                              hipStream_t stream)
{
    const float* text = (const float*)d_in[0];
    const float* Wq = (const float*)d_in[1];
    const float* bq = (const float*)d_in[2];
    const float* Wk = (const float*)d_in[3];
    const float* bk = (const float*)d_in[4];
    const float* Wv = (const float*)d_in[5];
    const float* bv = (const float*)d_in[6];
    const float* Wo = (const float*)d_in[7];
    const float* bo = (const float*)d_in[8];
    float* out = (float*)d_out;

    // ws layout (bf16): Xb | Wqkvt | Wot | Q | K | Vt | Attb  (~49 MB)
    ushort_t* Xb    = (ushort_t*)d_ws;
    ushort_t* Wqkvt = Xb + (size_t)MROWS * TDIM;
    ushort_t* Wot   = Wqkvt + (size_t)NQKV * TDIM;
    ushort_t* Qw    = Wot + (size_t)VDIM * HID;
    ushort_t* Kw    = Qw + (size_t)MROWS * HID;
    ushort_t* Vtw   = Kw + (size_t)MROWS * HID;
    ushort_t* Attb  = Vtw + (size_t)MROWS * HID;

    conv_x<<<dim3(MROWS * TDIM / 1024), 256, 0, stream>>>(text, Xb);
    transp_w<<<dim3(24, 24, 4), 256, 0, stream>>>(Wq, Wk, Wv, Wo, Wqkvt, Wot);
    qkv_gemm_mfma<<<dim3(12, 64), 256, 0, stream>>>(Xb, Wqkvt, bq, bk, bv, Qw, Kw, Vtw);
    flash_attn_mfma<<<dim3(16, 32), 512, 0, stream>>>(Qw, Kw, Vtw, Attb);
    out_gemm_mfma<<<dim3(6, 64), 256, 0, stream>>>(Attb, Wot, bo, out);
}

// Round 8
// 219.252 us; speedup vs baseline: 1.2796x; 1.2796x over previous
//
#include <hip/hip_runtime.h>
#include <hip/hip_bf16.h>

// B=4, S=2048, TEXT_DIM=768, VISION_DIM=768, HIDDEN=512, HEADS=8, HEAD_DIM=64
#define BATCH 4
#define SEQ 2048
#define TDIM 768
#define VDIM 768
#define HID 512
#define NHEADS 8
#define HDIM 64
#define MROWS (BATCH * SEQ)   // 8192
#define NQKV (3 * HID)        // 1536

typedef unsigned short ushort_t;
typedef __attribute__((ext_vector_type(8))) short short8;
typedef __attribute__((ext_vector_type(4))) short short4v;
typedef __attribute__((ext_vector_type(4))) float floatx4;

// 0.125 * log2(e): folded into Q so softmax uses exp2
#define QSCALE 0.18033688011112042f

__device__ __forceinline__ ushort_t bf16_rne(float f) {
    unsigned int u = __float_as_uint(f);
    u = (u + 0x7fffu + ((u >> 16) & 1u)) >> 16;
    return (ushort_t)u;
}

__device__ __forceinline__ void async16(const ushort_t* g, ushort_t* l) {
    __builtin_amdgcn_global_load_lds(
        (const __attribute__((address_space(1))) unsigned int*)g,
        (__attribute__((address_space(3))) unsigned int*)l, 16, 0, 0);
}

// ---------------------------------------------------------------------------
// Pre-pass A: X fp32 -> bf16 (8192x768)
// ---------------------------------------------------------------------------
__global__ __launch_bounds__(256) void conv_x(const float* __restrict__ X,
                                              ushort_t* __restrict__ Xb)
{
    const int i = (blockIdx.x * 256 + threadIdx.x) * 4;
    const floatx4 v = *(const floatx4*)(X + i);
    short4v o;
#pragma unroll
    for (int j = 0; j < 4; ++j) o[j] = (short)bf16_rne(v[j]);
    *(short4v*)(Xb + i) = o;
}

// ---------------------------------------------------------------------------
// Pre-pass B: weight transposes -> bf16 [N][K].
// ---------------------------------------------------------------------------
__global__ __launch_bounds__(256) void transp_w(
    const float* __restrict__ Wq, const float* __restrict__ Wk,
    const float* __restrict__ Wv, const float* __restrict__ Wo,
    ushort_t* __restrict__ Wqkvt, ushort_t* __restrict__ Wot)
{
    __shared__ float tile[32][33];
    const int z = blockIdx.z;
    const float* src;
    ushort_t* dst;
    int R, C;
    if (z < 3) {
        src = (z == 0) ? Wq : (z == 1) ? Wk : Wv;
        dst = Wqkvt + (size_t)z * HID * TDIM;
        R = TDIM; C = HID;
    } else {
        src = Wo; dst = Wot; R = HID; C = VDIM;
    }
    const int tx = threadIdx.x & 31, ty = threadIdx.x >> 5;  // 32 x 8
    const int c0 = blockIdx.x * 32, r0 = blockIdx.y * 32;
    if (c0 >= C || r0 >= R) return;
#pragma unroll
    for (int i = 0; i < 4; ++i)
        tile[ty + i * 8][tx] = src[(size_t)(r0 + ty + i * 8) * C + c0 + tx];
    __syncthreads();
#pragma unroll
    for (int i = 0; i < 4; ++i)
        dst[(size_t)(c0 + ty + i * 8) * R + r0 + tx] = bf16_rne(tile[tx][ty + i * 8]);
}

// ---------------------------------------------------------------------------
// Widened bf16 MFMA GEMM mainloop: C(128x256) = A[M][K] x Bt[N][K]^T.
// Round-8 change vs gemm128 (128x128): wave-col stride 128, acc[4][8].
// Per half-K-step: 12 ds_read_b128 (4 af + 8 bf) feed 32 MFMAs
// (144 LDS-cyc vs 155 MFMA-cyc -> MFMA-bound; old 8:16 was LDS-bound),
// and 64 MFMA/wave between barriers (2x old) amortizes the sync drain.
// Staging/barrier idiom identical to the verified gemm128.
// ---------------------------------------------------------------------------
template<int KD, bool SWAPPED>
__device__ __forceinline__ void gemm256(
    const ushort_t* __restrict__ A, const ushort_t* __restrict__ Bt,
    int m0, int n0, ushort_t* As, ushort_t* Bs, floatx4 (&acc)[4][8])
{
    const int tid  = threadIdx.x;
    const int lane = tid & 63;
    const int w    = tid >> 6;     // 0..3
    const int l15  = lane & 15;
    const int quad = lane >> 4;
    const int wrow = w >> 1;       // M half (64 rows)
    const int wcol = w & 1;        // N half (128 cols)

    const int srow = lane >> 3;        // 0..7
    const int scol = (lane & 7) * 8;   // k elem offset

    const ushort_t* ga = A  + (size_t)(m0 + w * 32 + srow) * KD + scol;
    const ushort_t* gb = Bt + (size_t)(n0 + w * 64 + srow) * KD + scol;
    ushort_t* la = As + (w * 32) * 64;
    ushort_t* lb = Bs + (w * 64) * 64;

    for (int kt = 0; kt < KD; kt += 64) {
#pragma unroll
        for (int i = 0; i < 4; ++i)
            async16(ga + (size_t)(i * 8) * KD + kt, la + i * 8 * 64);
#pragma unroll
        for (int i = 0; i < 8; ++i)
            async16(gb + (size_t)(i * 8) * KD + kt, lb + i * 8 * 64);
        __syncthreads();
#pragma unroll
        for (int half = 0; half < 2; ++half) {
            const int kk = half * 32 + quad * 8;
            short8 af[4], bf[8];
#pragma unroll
            for (int t = 0; t < 4; ++t)
                af[t] = *(const short8*)&As[(wrow * 64 + t * 16 + l15) * 64 + kk];
#pragma unroll
            for (int t = 0; t < 8; ++t)
                bf[t] = *(const short8*)&Bs[(wcol * 128 + t * 16 + l15) * 64 + kk];
#pragma unroll
            for (int mi = 0; mi < 4; ++mi)
#pragma unroll
                for (int ni = 0; ni < 8; ++ni) {
                    if (SWAPPED)
                        acc[mi][ni] = __builtin_amdgcn_mfma_f32_16x16x32_bf16(
                            bf[ni], af[mi], acc[mi][ni], 0, 0, 0);
                    else
                        acc[mi][ni] = __builtin_amdgcn_mfma_f32_16x16x32_bf16(
                            af[mi], bf[ni], acc[mi][ni], 0, 0, 0);
                }
        }
        __syncthreads();
    }
}

// ---------------------------------------------------------------------------
// Kernel 1: QKV projection, bf16 MFMA.  Grid (6, 64); n-tile 256.
// ---------------------------------------------------------------------------
__global__ __launch_bounds__(256) void qkv_gemm_mfma(
    const ushort_t* __restrict__ Xb, const ushort_t* __restrict__ Wt,
    const float* __restrict__ bq, const float* __restrict__ bk,
    const float* __restrict__ bv,
    ushort_t* __restrict__ Q, ushort_t* __restrict__ K, ushort_t* __restrict__ V)
{
    __shared__ __align__(16) ushort_t As[128 * 64];
    __shared__ __align__(16) ushort_t Bs[256 * 64];

    const int bx = blockIdx.x;          // 0..5
    const int m0 = blockIdx.y * 128;
    const int n0 = bx * 256;
    const int which = bx >> 1;          // 0=Q 1=K 2=V (256-tiles align to 512)
    const bool isV = (which == 2);

    floatx4 acc[4][8];
#pragma unroll
    for (int i = 0; i < 4; ++i)
#pragma unroll
        for (int j = 0; j < 8; ++j) acc[i][j] = (floatx4)0.0f;

    if (isV) gemm256<TDIM, false>(Xb, Wt, m0, n0, As, Bs, acc);
    else     gemm256<TDIM, true >(Xb, Wt, m0, n0, As, Bs, acc);

    const int lane = threadIdx.x & 63;
    const int w    = threadIdx.x >> 6;
    const int l15  = lane & 15;
    const int quad = lane >> 4;
    const int wrow = w >> 1;
    const int wcol = w & 1;

    if (!isV) {
        const float* bias = (which == 0) ? bq : bk;
        const float scale = (which == 0) ? QSCALE : 1.0f;
        ushort_t* Out = (which == 0) ? Q : K;
#pragma unroll
        for (int mi = 0; mi < 4; ++mi) {
            const int m = m0 + wrow * 64 + mi * 16 + l15;
            const int b = m >> 11;
            const int s = m & 2047;
#pragma unroll
            for (int ni = 0; ni < 8; ++ni) {
                const int c = (n0 - which * HID) + wcol * 128 + ni * 16 + quad * 4;
                const int h = c >> 6;
                const int d0 = c & 63;
                const floatx4 b4 = *(const floatx4*)(bias + c);
                short4v pk;
#pragma unroll
                for (int r = 0; r < 4; ++r)
                    pk[r] = (short)bf16_rne((acc[mi][ni][r] + b4[r]) * scale);
                *(short4v*)&Out[((size_t)(b * NHEADS + h) * SEQ + s) * HDIM + d0] = pk;
            }
        }
    } else {
#pragma unroll
        for (int ni = 0; ni < 8; ++ni) {
            const int c = (n0 - 2 * HID) + wcol * 128 + ni * 16 + l15;
            const int h = c >> 6;
            const int d = c & 63;
            const float b1 = bv[c];
#pragma unroll
            for (int mi = 0; mi < 4; ++mi) {
                const int mb = m0 + wrow * 64 + mi * 16 + quad * 4;
                const int b = mb >> 11;
                const int s0 = mb & 2047;
                short4v pk;
#pragma unroll
                for (int r = 0; r < 4; ++r)
                    pk[r] = (short)bf16_rne(acc[mi][ni][r] + b1);
                *(short4v*)&V[((size_t)(b * NHEADS + h) * HDIM + d) * SEQ + s0] = pk;
            }
        }
    }
}

// ---------------------------------------------------------------------------
// Kernel 2: MFMA flash attention — v3 VERBATIM (round-1 source: measured
// 47.7 us, passed, absmax 4.88e-4). 512 threads = 8 waves; Q-tile 128.
// Do not touch: dual-qi (2x) failed correctness; direct-global K (v7) was
// latency-bound (134 us, MfmaUtil 11%).
// ---------------------------------------------------------------------------
__global__ __launch_bounds__(512) void flash_attn_mfma(
    const ushort_t* __restrict__ Q, const ushort_t* __restrict__ K,
    const ushort_t* __restrict__ Vt, ushort_t* __restrict__ Att)
{
    __shared__ __align__(16) ushort_t Ks[2][64 * 64];   // [buf][kk][d]  (swizzled)
    __shared__ __align__(16) ushort_t Vs[2][64 * 64];   // [buf][d][kk]  (swizzled)

    const int tid  = threadIdx.x;
    const int lane = tid & 63;
    const int w    = tid >> 6;     // wave 0..7
    const int l15  = lane & 15;
    const int quad = lane >> 4;

    const int bh = blockIdx.y;
    const int b  = bh >> 3;
    const int h  = bh & 7;
    const int q0 = blockIdx.x * 128;

    const ushort_t* Qb = Q  + (size_t)bh * SEQ * HDIM;
    const ushort_t* Kb = K  + (size_t)bh * SEQ * HDIM;
    const ushort_t* Vb = Vt + (size_t)bh * HDIM * SEQ;

    // Q fragments (registers, whole kernel). B-operand: n=q=l15, k=d=quad*8+j
    short8 qf0, qf1;
    {
        const ushort_t* qrow = Qb + (size_t)(q0 + w * 16 + l15) * HDIM + quad * 8;
        qf0 = *(const short8*)(qrow);
        qf1 = *(const short8*)(qrow + 32);
    }

    floatx4 of[4];
#pragma unroll
    for (int t = 0; t < 4; ++t) of[t] = (floatx4)0.0f;
    floatx4 ofl = (floatx4)0.0f;          // l accumulator via ones-MFMA

    short8 ones;
#pragma unroll
    for (int j = 0; j < 8; ++j) ones[j] = (short)0x3F80;   // bf16 1.0

    const floatx4 z4 = (floatx4)0.0f;

    // staging: wave w stages rows w*8..w*8+7 of each tile.
    // global source col16 is pre-swizzled so the LINEAR global_load_lds dest
    // (base + lane*16) lands the XOR-swizzled layout.
    const int srow = lane >> 3;                    // 0..7 = row&7
    const int scol = ((lane & 7) ^ srow) * 8;      // swizzled col (elems)
    const ushort_t* gk = Kb + (size_t)(w * 8 + srow) * HDIM + scol;
    const ushort_t* gv = Vb + (size_t)(w * 8 + srow) * SEQ + scol;
    ushort_t* lk0 = &Ks[0][w * 8 * 64];            // wave-uniform LDS bases
    ushort_t* lk1 = &Ks[1][w * 8 * 64];
    ushort_t* lv0 = &Vs[0][w * 8 * 64];
    ushort_t* lv1 = &Vs[1][w * 8 * 64];

    // fragment read offsets (swizzle-aware): global col16 c of row r sits at
    // LDS slot c ^ (r&7); r&7 == l15&7 for all t (t*16 = 0 mod 8).
    const int off0 = (quad ^ (l15 & 7)) * 8;       // elems, kv/d half 0
    const int off1 = off0 ^ 32;                    // (slot^4)*8, half 1

    auto tile = [&](const ushort_t* Kt, const ushort_t* Vt_) {
        // ---- S^T = K . Q^T ----
        floatx4 sacc[4];
        __builtin_amdgcn_s_setprio(1);
#pragma unroll
        for (int t = 0; t < 4; ++t) {
            const short8 kf0 = *(const short8*)&Kt[(t * 16 + l15) * 64 + off0];
            const short8 kf1 = *(const short8*)&Kt[(t * 16 + l15) * 64 + off1];
            floatx4 a = z4;
            a = __builtin_amdgcn_mfma_f32_16x16x32_bf16(kf0, qf0, a, 0, 0, 0);
            a = __builtin_amdgcn_mfma_f32_16x16x32_bf16(kf1, qf1, a, 0, 0, 0);
            sacc[t] = a;
        }
        __builtin_amdgcn_s_setprio(0);

        // ---- p = exp2(s) (raw v_exp_f32), pack pairs to bf16x2 ----
        // lane holds p for q=l15, kv = 16t + 4*quad + r
        unsigned w0[4], w1[4];
#pragma unroll
        for (int t = 0; t < 4; ++t) {
            const float p0 = __builtin_amdgcn_exp2f(sacc[t][0]);
            const float p1 = __builtin_amdgcn_exp2f(sacc[t][1]);
            const float p2 = __builtin_amdgcn_exp2f(sacc[t][2]);
            const float p3 = __builtin_amdgcn_exp2f(sacc[t][3]);
            asm("v_cvt_pk_bf16_f32 %0, %1, %2" : "=v"(w0[t]) : "v"(p0), "v"(p1));
            asm("v_cvt_pk_bf16_f32 %0, %1, %2" : "=v"(w1[t]) : "v"(p2), "v"(p3));
        }

        // ---- in-register P^T redistribution (dest b5'=t, b4'=src b5) ----
        unsigned a0 = w0[0], b0 = w0[1];
        asm("v_permlane32_swap_b32 %0, %1" : "+v"(a0), "+v"(b0));
        asm("v_permlane16_swap_b32 %0, %1" : "+v"(a0), "+v"(b0));
        unsigned a1 = w1[0], b1 = w1[1];
        asm("v_permlane32_swap_b32 %0, %1" : "+v"(a1), "+v"(b1));
        asm("v_permlane16_swap_b32 %0, %1" : "+v"(a1), "+v"(b1));
        unsigned a2 = w0[2], b2 = w0[3];
        asm("v_permlane32_swap_b32 %0, %1" : "+v"(a2), "+v"(b2));
        asm("v_permlane16_swap_b32 %0, %1" : "+v"(a2), "+v"(b2));
        unsigned a3 = w1[2], b3 = w1[3];
        asm("v_permlane32_swap_b32 %0, %1" : "+v"(a3), "+v"(b3));
        asm("v_permlane16_swap_b32 %0, %1" : "+v"(a3), "+v"(b3));

        union { unsigned u[4]; short8 s; } P0, P1;
        P0.u[0] = a0; P0.u[1] = a1; P0.u[2] = b0; P0.u[3] = b1;   // kv 0..31
        P1.u[0] = a2; P1.u[1] = a3; P1.u[2] = b2; P1.u[3] = b3;   // kv 32..63
        const short8 pf0 = P0.s;
        const short8 pf1 = P1.s;

        // ---- O^T += V^T . P^T ; l += 1 . P^T (MFMA pipe) ----
        __builtin_amdgcn_s_setprio(1);
        ofl = __builtin_amdgcn_mfma_f32_16x16x32_bf16(ones, pf0, ofl, 0, 0, 0);
        ofl = __builtin_amdgcn_mfma_f32_16x16x32_bf16(ones, pf1, ofl, 0, 0, 0);
#pragma unroll
        for (int t = 0; t < 4; ++t) {
            const short8 vf0 = *(const short8*)&Vt_[(t * 16 + l15) * 64 + off0];
            const short8 vf1 = *(const short8*)&Vt_[(t * 16 + l15) * 64 + off1];
            of[t] = __builtin_amdgcn_mfma_f32_16x16x32_bf16(vf0, pf0, of[t], 0, 0, 0);
            of[t] = __builtin_amdgcn_mfma_f32_16x16x32_bf16(vf1, pf1, of[t], 0, 0, 0);
        }
        __builtin_amdgcn_s_setprio(0);
    };

    // prologue: tile 0 into buf0
    async16(gk, lk0);
    async16(gv, lv0);

    for (int kt = 0; kt < SEQ; kt += 128) {
        __syncthreads();                       // drains buf0 loads (vmcnt(0))
        async16(gk + (size_t)(kt + 64) * HDIM, lk1);   // prefetch buf1
        async16(gv + (kt + 64), lv1);
        tile(Ks[0], Vs[0]);

        __syncthreads();                       // drains buf1 loads
        if (kt + 128 < SEQ) {
            async16(gk + (size_t)(kt + 128) * HDIM, lk0);  // prefetch buf0
            async16(gv + (kt + 128), lv0);
        }
        tile(Ks[1], Vs[1]);
    }

    // ---- epilogue: each lane already holds full l for its q=l15 ----
    const float inv = 1.f / ofl[0];

    const int s = q0 + w * 16 + l15;
    ushort_t* arow = Att + ((size_t)(b * SEQ + s)) * HID + h * HDIM;
#pragma unroll
    for (int t = 0; t < 4; ++t) {
        short4v pk;
#pragma unroll
        for (int r = 0; r < 4; ++r) pk[r] = (short)bf16_rne(of[t][r] * inv);
        *(short4v*)&arow[t * 16 + quad * 4] = pk;
    }
}

// ---------------------------------------------------------------------------
// Kernel 3: output projection, bf16 MFMA.  Grid (3, 64); n-tile 256.
// ---------------------------------------------------------------------------
__global__ __launch_bounds__(256) void out_gemm_mfma(
    const ushort_t* __restrict__ Attb, const ushort_t* __restrict__ Wot,
    const float* __restrict__ bo, float* __restrict__ Y)
{
    __shared__ __align__(16) ushort_t As[128 * 64];
    __shared__ __align__(16) ushort_t Bs[256 * 64];

    const int m0 = blockIdx.y * 128;
    const int n0 = blockIdx.x * 256;

    floatx4 acc[4][8];
#pragma unroll
    for (int i = 0; i < 4; ++i)
#pragma unroll
        for (int j = 0; j < 8; ++j) acc[i][j] = (floatx4)0.0f;

    gemm256<HID, true>(Attb, Wot, m0, n0, As, Bs, acc);

    const int lane = threadIdx.x & 63;
    const int w    = threadIdx.x >> 6;
    const int l15  = lane & 15;
    const int quad = lane >> 4;
    const int wrow = w >> 1;
    const int wcol = w & 1;

#pragma unroll
    for (int mi = 0; mi < 4; ++mi) {
        const int m = m0 + wrow * 64 + mi * 16 + l15;
#pragma unroll
        for (int ni = 0; ni < 8; ++ni) {
            const int nb = n0 + wcol * 128 + ni * 16 + quad * 4;
            const floatx4 b4 = *(const floatx4*)(bo + nb);
            floatx4 o;
#pragma unroll
            for (int r = 0; r < 4; ++r) o[r] = acc[mi][ni][r] + b4[r];
            *(floatx4*)&Y[(size_t)m * VDIM + nb] = o;
        }
    }
}

// ---------------------------------------------------------------------------
extern "C" void kernel_launch(void* const* d_in, const int* in_sizes, int n_in,
                              void* d_out, int out_size, void* d_ws, size_t ws_size,
                              hipStream_t stream)
{
    const float* text = (const float*)d_in[0];
    const float* Wq = (const float*)d_in[1];
    const float* bq = (const float*)d_in[2];
    const float* Wk = (const float*)d_in[3];
    const float* bk = (const float*)d_in[4];
    const float* Wv = (const float*)d_in[5];
    const float* bv = (const float*)d_in[6];
    const float* Wo = (const float*)d_in[7];
    const float* bo = (const float*)d_in[8];
    float* out = (float*)d_out;

    // ws layout (bf16): Xb | Wqkvt | Wot | Q | K | Vt | Attb  (~49 MB)
    ushort_t* Xb    = (ushort_t*)d_ws;
    ushort_t* Wqkvt = Xb + (size_t)MROWS * TDIM;
    ushort_t* Wot   = Wqkvt + (size_t)NQKV * TDIM;
    ushort_t* Qw    = Wot + (size_t)VDIM * HID;
    ushort_t* Kw    = Qw + (size_t)MROWS * HID;
    ushort_t* Vtw   = Kw + (size_t)MROWS * HID;
    ushort_t* Attb  = Vtw + (size_t)MROWS * HID;

    conv_x<<<dim3(MROWS * TDIM / 1024), 256, 0, stream>>>(text, Xb);
    transp_w<<<dim3(24, 24, 4), 256, 0, stream>>>(Wq, Wk, Wv, Wo, Wqkvt, Wot);
    qkv_gemm_mfma<<<dim3(6, 64), 256, 0, stream>>>(Xb, Wqkvt, bq, bk, bv, Qw, Kw, Vtw);
    flash_attn_mfma<<<dim3(16, 32), 512, 0, stream>>>(Qw, Kw, Vtw, Attb);
    out_gemm_mfma<<<dim3(3, 64), 256, 0, stream>>>(Attb, Wot, bo, out);
}

// Round 9
// 185.474 us; speedup vs baseline: 1.5126x; 1.1821x over previous
//
#include <hip/hip_runtime.h>
#include <hip/hip_bf16.h>

// B=4, S=2048, TEXT_DIM=768, VISION_DIM=768, HIDDEN=512, HEADS=8, HEAD_DIM=64
#define BATCH 4
#define SEQ 2048
#define TDIM 768
#define VDIM 768
#define HID 512
#define NHEADS 8
#define HDIM 64
#define MROWS (BATCH * SEQ)   // 8192
#define NQKV (3 * HID)        // 1536

typedef unsigned short ushort_t;
typedef __attribute__((ext_vector_type(8))) short short8;
typedef __attribute__((ext_vector_type(4))) short short4v;
typedef __attribute__((ext_vector_type(4))) float floatx4;

// 0.125 * log2(e): folded into Q so softmax uses exp2
#define QSCALE 0.18033688011112042f

__device__ __forceinline__ ushort_t bf16_rne(float f) {
    unsigned int u = __float_as_uint(f);
    u = (u + 0x7fffu + ((u >> 16) & 1u)) >> 16;
    return (ushort_t)u;
}

__device__ __forceinline__ void async16(const ushort_t* g, ushort_t* l) {
    __builtin_amdgcn_global_load_lds(
        (const __attribute__((address_space(1))) unsigned int*)g,
        (__attribute__((address_space(3))) unsigned int*)l, 16, 0, 0);
}

// ---------------------------------------------------------------------------
// Pre-pass A: X fp32 -> bf16 (8192x768)
// ---------------------------------------------------------------------------
__global__ __launch_bounds__(256) void conv_x(const float* __restrict__ X,
                                              ushort_t* __restrict__ Xb)
{
    const int i = (blockIdx.x * 256 + threadIdx.x) * 4;
    const floatx4 v = *(const floatx4*)(X + i);
    short4v o;
#pragma unroll
    for (int j = 0; j < 4; ++j) o[j] = (short)bf16_rne(v[j]);
    *(short4v*)(Xb + i) = o;
}

// ---------------------------------------------------------------------------
// Pre-pass B: weight transposes -> bf16 [N][K].
// ---------------------------------------------------------------------------
__global__ __launch_bounds__(256) void transp_w(
    const float* __restrict__ Wq, const float* __restrict__ Wk,
    const float* __restrict__ Wv, const float* __restrict__ Wo,
    ushort_t* __restrict__ Wqkvt, ushort_t* __restrict__ Wot)
{
    __shared__ float tile[32][33];
    const int z = blockIdx.z;
    const float* src;
    ushort_t* dst;
    int R, C;
    if (z < 3) {
        src = (z == 0) ? Wq : (z == 1) ? Wk : Wv;
        dst = Wqkvt + (size_t)z * HID * TDIM;
        R = TDIM; C = HID;
    } else {
        src = Wo; dst = Wot; R = HID; C = VDIM;
    }
    const int tx = threadIdx.x & 31, ty = threadIdx.x >> 5;  // 32 x 8
    const int c0 = blockIdx.x * 32, r0 = blockIdx.y * 32;
    if (c0 >= C || r0 >= R) return;
#pragma unroll
    for (int i = 0; i < 4; ++i)
        tile[ty + i * 8][tx] = src[(size_t)(r0 + ty + i * 8) * C + c0 + tx];
    __syncthreads();
#pragma unroll
    for (int i = 0; i < 4; ++i)
        dst[(size_t)(c0 + ty + i * 8) * R + r0 + tx] = bf16_rne(tile[tx][ty + i * 8]);
}

// ---------------------------------------------------------------------------
// m97-style bf16 MFMA GEMM mainloop: C(128x128) = A[M][K] x Bt[N][K]^T.
// Round-9 change: XOR-swizzled LDS (flash's verified pattern).
// Round-8 counters showed SQ_LDS_BANK_CONFLICT=5.3M on the GEMM: the
// [row][64] tile has 128B row stride, so a quad's 16 lanes (same kk) hit one
// 4-bank group -> 16-way conflict (~5.7x, m136). Fix = the involution flash
// uses with 0 conflicts: stage with pre-swizzled GLOBAL col
// (scol = ((lane&7)^srow)*8, LDS dest linear), read slot c^(row&7):
// kk = ((half*4+quad) ^ (l15&7))*8.  LDS[r][s] = G[r][s^(r&7)] both sides.
// ---------------------------------------------------------------------------
template<int KD, bool SWAPPED>
__device__ __forceinline__ void gemm128(
    const ushort_t* __restrict__ A, const ushort_t* __restrict__ Bt,
    int m0, int n0, ushort_t* As, ushort_t* Bs, floatx4 (&acc)[4][4])
{
    const int tid  = threadIdx.x;
    const int lane = tid & 63;
    const int w    = tid >> 6;
    const int l15  = lane & 15;
    const int quad = lane >> 4;
    const int wrow = w >> 1;
    const int wcol = w & 1;

    const int srow = lane >> 3;                  // 0..7 = row&7
    const int scol = ((lane & 7) ^ srow) * 8;    // swizzled k elem offset

    const ushort_t* ga = A  + (size_t)(m0 + w * 32 + srow) * KD + scol;
    const ushort_t* gb = Bt + (size_t)(n0 + w * 32 + srow) * KD + scol;
    ushort_t* la = As + (w * 32) * 64;
    ushort_t* lb = Bs + (w * 32) * 64;

    for (int kt = 0; kt < KD; kt += 64) {
#pragma unroll
        for (int i = 0; i < 4; ++i) {
            async16(ga + (size_t)(i * 8) * KD + kt, la + i * 8 * 64);
            async16(gb + (size_t)(i * 8) * KD + kt, lb + i * 8 * 64);
        }
        __syncthreads();
#pragma unroll
        for (int half = 0; half < 2; ++half) {
            // swizzle-aware read: rows of both As and Bs are == l15 (mod 8)
            const int kk = ((half * 4 + quad) ^ (l15 & 7)) * 8;
            short8 af[4], bf[4];
#pragma unroll
            for (int t = 0; t < 4; ++t) {
                af[t] = *(const short8*)&As[(wrow * 64 + t * 16 + l15) * 64 + kk];
                bf[t] = *(const short8*)&Bs[(wcol * 64 + t * 16 + l15) * 64 + kk];
            }
#pragma unroll
            for (int mi = 0; mi < 4; ++mi)
#pragma unroll
                for (int ni = 0; ni < 4; ++ni) {
                    if (SWAPPED)
                        acc[mi][ni] = __builtin_amdgcn_mfma_f32_16x16x32_bf16(
                            bf[ni], af[mi], acc[mi][ni], 0, 0, 0);
                    else
                        acc[mi][ni] = __builtin_amdgcn_mfma_f32_16x16x32_bf16(
                            af[mi], bf[ni], acc[mi][ni], 0, 0, 0);
                }
        }
        __syncthreads();
    }
}

// ---------------------------------------------------------------------------
// Kernel 1: QKV projection, bf16 MFMA.  Grid (12, 64) — round-1 config.
// ---------------------------------------------------------------------------
__global__ __launch_bounds__(256) void qkv_gemm_mfma(
    const ushort_t* __restrict__ Xb, const ushort_t* __restrict__ Wt,
    const float* __restrict__ bq, const float* __restrict__ bk,
    const float* __restrict__ bv,
    ushort_t* __restrict__ Q, ushort_t* __restrict__ K, ushort_t* __restrict__ V)
{
    __shared__ __align__(16) ushort_t As[128 * 64];
    __shared__ __align__(16) ushort_t Bs[128 * 64];

    const int bx = blockIdx.x;          // 0..11
    const int m0 = blockIdx.y * 128;
    const int n0 = bx * 128;
    const int which = bx >> 2;          // 0=Q 1=K 2=V
    const bool isV = (which == 2);

    floatx4 acc[4][4];
#pragma unroll
    for (int i = 0; i < 4; ++i)
#pragma unroll
        for (int j = 0; j < 4; ++j) acc[i][j] = (floatx4)0.0f;

    if (isV) gemm128<TDIM, false>(Xb, Wt, m0, n0, As, Bs, acc);
    else     gemm128<TDIM, true >(Xb, Wt, m0, n0, As, Bs, acc);

    const int lane = threadIdx.x & 63;
    const int w    = threadIdx.x >> 6;
    const int l15  = lane & 15;
    const int quad = lane >> 4;
    const int wrow = w >> 1;
    const int wcol = w & 1;

    if (!isV) {
        const float* bias = (which == 0) ? bq : bk;
        const float scale = (which == 0) ? QSCALE : 1.0f;
        ushort_t* Out = (which == 0) ? Q : K;
#pragma unroll
        for (int mi = 0; mi < 4; ++mi) {
            const int m = m0 + wrow * 64 + mi * 16 + l15;
            const int b = m >> 11;
            const int s = m & 2047;
#pragma unroll
            for (int ni = 0; ni < 4; ++ni) {
                const int c = (n0 - which * HID) + wcol * 64 + ni * 16 + quad * 4;
                const int h = c >> 6;
                const int d0 = c & 63;
                const floatx4 b4 = *(const floatx4*)(bias + c);
                short4v pk;
#pragma unroll
                for (int r = 0; r < 4; ++r)
                    pk[r] = (short)bf16_rne((acc[mi][ni][r] + b4[r]) * scale);
                *(short4v*)&Out[((size_t)(b * NHEADS + h) * SEQ + s) * HDIM + d0] = pk;
            }
        }
    } else {
#pragma unroll
        for (int ni = 0; ni < 4; ++ni) {
            const int c = (n0 - 2 * HID) + wcol * 64 + ni * 16 + l15;
            const int h = c >> 6;
            const int d = c & 63;
            const float b1 = bv[c];
#pragma unroll
            for (int mi = 0; mi < 4; ++mi) {
                const int mb = m0 + wrow * 64 + mi * 16 + quad * 4;
                const int b = mb >> 11;
                const int s0 = mb & 2047;
                short4v pk;
#pragma unroll
                for (int r = 0; r < 4; ++r)
                    pk[r] = (short)bf16_rne(acc[mi][ni][r] + b1);
                *(short4v*)&V[((size_t)(b * NHEADS + h) * HDIM + d) * SEQ + s0] = pk;
            }
        }
    }
}

// ---------------------------------------------------------------------------
// Kernel 2: MFMA flash attention — v3 VERBATIM (round-1: 47.7 us, passed).
// Do not touch: dual-qi (2x) failed correctness; direct-global K (v7) was
// latency-bound (134 us, MfmaUtil 11%).
// ---------------------------------------------------------------------------
__global__ __launch_bounds__(512) void flash_attn_mfma(
    const ushort_t* __restrict__ Q, const ushort_t* __restrict__ K,
    const ushort_t* __restrict__ Vt, ushort_t* __restrict__ Att)
{
    __shared__ __align__(16) ushort_t Ks[2][64 * 64];   // [buf][kk][d]  (swizzled)
    __shared__ __align__(16) ushort_t Vs[2][64 * 64];   // [buf][d][kk]  (swizzled)

    const int tid  = threadIdx.x;
    const int lane = tid & 63;
    const int w    = tid >> 6;     // wave 0..7
    const int l15  = lane & 15;
    const int quad = lane >> 4;

    const int bh = blockIdx.y;
    const int b  = bh >> 3;
    const int h  = bh & 7;
    const int q0 = blockIdx.x * 128;

    const ushort_t* Qb = Q  + (size_t)bh * SEQ * HDIM;
    const ushort_t* Kb = K  + (size_t)bh * SEQ * HDIM;
    const ushort_t* Vb = Vt + (size_t)bh * HDIM * SEQ;

    // Q fragments (registers, whole kernel). B-operand: n=q=l15, k=d=quad*8+j
    short8 qf0, qf1;
    {
        const ushort_t* qrow = Qb + (size_t)(q0 + w * 16 + l15) * HDIM + quad * 8;
        qf0 = *(const short8*)(qrow);
        qf1 = *(const short8*)(qrow + 32);
    }

    floatx4 of[4];
#pragma unroll
    for (int t = 0; t < 4; ++t) of[t] = (floatx4)0.0f;
    floatx4 ofl = (floatx4)0.0f;          // l accumulator via ones-MFMA

    short8 ones;
#pragma unroll
    for (int j = 0; j < 8; ++j) ones[j] = (short)0x3F80;   // bf16 1.0

    const floatx4 z4 = (floatx4)0.0f;

    // staging: wave w stages rows w*8..w*8+7 of each tile.
    // global source col16 is pre-swizzled so the LINEAR global_load_lds dest
    // (base + lane*16) lands the XOR-swizzled layout.
    const int srow = lane >> 3;                    // 0..7 = row&7
    const int scol = ((lane & 7) ^ srow) * 8;      // swizzled col (elems)
    const ushort_t* gk = Kb + (size_t)(w * 8 + srow) * HDIM + scol;
    const ushort_t* gv = Vb + (size_t)(w * 8 + srow) * SEQ + scol;
    ushort_t* lk0 = &Ks[0][w * 8 * 64];            // wave-uniform LDS bases
    ushort_t* lk1 = &Ks[1][w * 8 * 64];
    ushort_t* lv0 = &Vs[0][w * 8 * 64];
    ushort_t* lv1 = &Vs[1][w * 8 * 64];

    // fragment read offsets (swizzle-aware): global col16 c of row r sits at
    // LDS slot c ^ (r&7); r&7 == l15&7 for all t (t*16 = 0 mod 8).
    const int off0 = (quad ^ (l15 & 7)) * 8;       // elems, kv/d half 0
    const int off1 = off0 ^ 32;                    // (slot^4)*8, half 1

    auto tile = [&](const ushort_t* Kt, const ushort_t* Vt_) {
        // ---- S^T = K . Q^T ----
        floatx4 sacc[4];
        __builtin_amdgcn_s_setprio(1);
#pragma unroll
        for (int t = 0; t < 4; ++t) {
            const short8 kf0 = *(const short8*)&Kt[(t * 16 + l15) * 64 + off0];
            const short8 kf1 = *(const short8*)&Kt[(t * 16 + l15) * 64 + off1];
            floatx4 a = z4;
            a = __builtin_amdgcn_mfma_f32_16x16x32_bf16(kf0, qf0, a, 0, 0, 0);
            a = __builtin_amdgcn_mfma_f32_16x16x32_bf16(kf1, qf1, a, 0, 0, 0);
            sacc[t] = a;
        }
        __builtin_amdgcn_s_setprio(0);

        // ---- p = exp2(s) (raw v_exp_f32), pack pairs to bf16x2 ----
        // lane holds p for q=l15, kv = 16t + 4*quad + r
        unsigned w0[4], w1[4];
#pragma unroll
        for (int t = 0; t < 4; ++t) {
            const float p0 = __builtin_amdgcn_exp2f(sacc[t][0]);
            const float p1 = __builtin_amdgcn_exp2f(sacc[t][1]);
            const float p2 = __builtin_amdgcn_exp2f(sacc[t][2]);
            const float p3 = __builtin_amdgcn_exp2f(sacc[t][3]);
            asm("v_cvt_pk_bf16_f32 %0, %1, %2" : "=v"(w0[t]) : "v"(p0), "v"(p1));
            asm("v_cvt_pk_bf16_f32 %0, %1, %2" : "=v"(w1[t]) : "v"(p2), "v"(p3));
        }

        // ---- in-register P^T redistribution (dest b5'=t, b4'=src b5) ----
        unsigned a0 = w0[0], b0 = w0[1];
        asm("v_permlane32_swap_b32 %0, %1" : "+v"(a0), "+v"(b0));
        asm("v_permlane16_swap_b32 %0, %1" : "+v"(a0), "+v"(b0));
        unsigned a1 = w1[0], b1 = w1[1];
        asm("v_permlane32_swap_b32 %0, %1" : "+v"(a1), "+v"(b1));
        asm("v_permlane16_swap_b32 %0, %1" : "+v"(a1), "+v"(b1));
        unsigned a2 = w0[2], b2 = w0[3];
        asm("v_permlane32_swap_b32 %0, %1" : "+v"(a2), "+v"(b2));
        asm("v_permlane16_swap_b32 %0, %1" : "+v"(a2), "+v"(b2));
        unsigned a3 = w1[2], b3 = w1[3];
        asm("v_permlane32_swap_b32 %0, %1" : "+v"(a3), "+v"(b3));
        asm("v_permlane16_swap_b32 %0, %1" : "+v"(a3), "+v"(b3));

        union { unsigned u[4]; short8 s; } P0, P1;
        P0.u[0] = a0; P0.u[1] = a1; P0.u[2] = b0; P0.u[3] = b1;   // kv 0..31
        P1.u[0] = a2; P1.u[1] = a3; P1.u[2] = b2; P1.u[3] = b3;   // kv 32..63
        const short8 pf0 = P0.s;
        const short8 pf1 = P1.s;

        // ---- O^T += V^T . P^T ; l += 1 . P^T (MFMA pipe) ----
        __builtin_amdgcn_s_setprio(1);
        ofl = __builtin_amdgcn_mfma_f32_16x16x32_bf16(ones, pf0, ofl, 0, 0, 0);
        ofl = __builtin_amdgcn_mfma_f32_16x16x32_bf16(ones, pf1, ofl, 0, 0, 0);
#pragma unroll
        for (int t = 0; t < 4; ++t) {
            const short8 vf0 = *(const short8*)&Vt_[(t * 16 + l15) * 64 + off0];
            const short8 vf1 = *(const short8*)&Vt_[(t * 16 + l15) * 64 + off1];
            of[t] = __builtin_amdgcn_mfma_f32_16x16x32_bf16(vf0, pf0, of[t], 0, 0, 0);
            of[t] = __builtin_amdgcn_mfma_f32_16x16x32_bf16(vf1, pf1, of[t], 0, 0, 0);
        }
        __builtin_amdgcn_s_setprio(0);
    };

    // prologue: tile 0 into buf0
    async16(gk, lk0);
    async16(gv, lv0);

    for (int kt = 0; kt < SEQ; kt += 128) {
        __syncthreads();                       // drains buf0 loads (vmcnt(0))
        async16(gk + (size_t)(kt + 64) * HDIM, lk1);   // prefetch buf1
        async16(gv + (kt + 64), lv1);
        tile(Ks[0], Vs[0]);

        __syncthreads();                       // drains buf1 loads
        if (kt + 128 < SEQ) {
            async16(gk + (size_t)(kt + 128) * HDIM, lk0);  // prefetch buf0
            async16(gv + (kt + 128), lv0);
        }
        tile(Ks[1], Vs[1]);
    }

    // ---- epilogue: each lane already holds full l for its q=l15 ----
    const float inv = 1.f / ofl[0];

    const int s = q0 + w * 16 + l15;
    ushort_t* arow = Att + ((size_t)(b * SEQ + s)) * HID + h * HDIM;
#pragma unroll
    for (int t = 0; t < 4; ++t) {
        short4v pk;
#pragma unroll
        for (int r = 0; r < 4; ++r) pk[r] = (short)bf16_rne(of[t][r] * inv);
        *(short4v*)&arow[t * 16 + quad * 4] = pk;
    }
}

// ---------------------------------------------------------------------------
// Kernel 3: output projection, bf16 MFMA.  Grid (6, 64) — round-1 config.
// ---------------------------------------------------------------------------
__global__ __launch_bounds__(256) void out_gemm_mfma(
    const ushort_t* __restrict__ Attb, const ushort_t* __restrict__ Wot,
    const float* __restrict__ bo, float* __restrict__ Y)
{
    __shared__ __align__(16) ushort_t As[128 * 64];
    __shared__ __align__(16) ushort_t Bs[128 * 64];

    const int m0 = blockIdx.y * 128;
    const int n0 = blockIdx.x * 128;

    floatx4 acc[4][4];
#pragma unroll
    for (int i = 0; i < 4; ++i)
#pragma unroll
        for (int j = 0; j < 4; ++j) acc[i][j] = (floatx4)0.0f;

    gemm128<HID, true>(Attb, Wot, m0, n0, As, Bs, acc);

    const int lane = threadIdx.x & 63;
    const int w    = threadIdx.x >> 6;
    const int l15  = lane & 15;
    const int quad = lane >> 4;
    const int wrow = w >> 1;
    const int wcol = w & 1;

#pragma unroll
    for (int mi = 0; mi < 4; ++mi) {
        const int m = m0 + wrow * 64 + mi * 16 + l15;
#pragma unroll
        for (int ni = 0; ni < 4; ++ni) {
            const int nb = n0 + wcol * 64 + ni * 16 + quad * 4;
            const floatx4 b4 = *(const floatx4*)(bo + nb);
            floatx4 o;
#pragma unroll
            for (int r = 0; r < 4; ++r) o[r] = acc[mi][ni][r] + b4[r];
            *(floatx4*)&Y[(size_t)m * VDIM + nb] = o;
        }
    }
}

// ---------------------------------------------------------------------------
extern "C" void kernel_launch(void* const* d_in, const int* in_sizes, int n_in,
                              void* d_out, int out_size, void* d_ws, size_t ws_size,
                              hipStream_t stream)
{
    const float* text = (const float*)d_in[0];
    const float* Wq = (const float*)d_in[1];
    const float* bq = (const float*)d_in[2];
    const float* Wk = (const float*)d_in[3];
    const float* bk = (const float*)d_in[4];
    const float* Wv = (const float*)d_in[5];
    const float* bv = (const float*)d_in[6];
    const float* Wo = (const float*)d_in[7];
    const float* bo = (const float*)d_in[8];
    float* out = (float*)d_out;

    // ws layout (bf16): Xb | Wqkvt | Wot | Q | K | Vt | Attb  (~49 MB)
    ushort_t* Xb    = (ushort_t*)d_ws;
    ushort_t* Wqkvt = Xb + (size_t)MROWS * TDIM;
    ushort_t* Wot   = Wqkvt + (size_t)NQKV * TDIM;
    ushort_t* Qw    = Wot + (size_t)VDIM * HID;
    ushort_t* Kw    = Qw + (size_t)MROWS * HID;
    ushort_t* Vtw   = Kw + (size_t)MROWS * HID;
    ushort_t* Attb  = Vtw + (size_t)MROWS * HID;

    conv_x<<<dim3(MROWS * TDIM / 1024), 256, 0, stream>>>(text, Xb);
    transp_w<<<dim3(24, 24, 4), 256, 0, stream>>>(Wq, Wk, Wv, Wo, Wqkvt, Wot);
    qkv_gemm_mfma<<<dim3(12, 64), 256, 0, stream>>>(Xb, Wqkvt, bq, bk, bv, Qw, Kw, Vtw);
    flash_attn_mfma<<<dim3(16, 32), 512, 0, stream>>>(Qw, Kw, Vtw, Attb);
    out_gemm_mfma<<<dim3(6, 64), 256, 0, stream>>>(Attb, Wot, bo, out);
}